// Round 2
// baseline (178.462 us; speedup 1.0000x reference)
//
#include <hip/hip_runtime.h>

#define ROI_OUT 7
#define ROI_SR 2
#define NCH 256
#define NROI_PER_B 512

struct RoiMeta {
    float x1, y1;      // scaled roi origin
    float sx, sy;      // per-grid-sample step = rw/14, rh/14 (scaled)
    int level, b;
    int pad0, pad1;
};

__global__ void prep_rois_kernel(const float* __restrict__ rois,
                                 RoiMeta* __restrict__ meta, int total) {
    int n = blockIdx.x * blockDim.x + threadIdx.x;
    if (n >= total) return;
    float x1 = rois[n * 4 + 0];
    float y1 = rois[n * 4 + 1];
    float x2 = rois[n * 4 + 2];
    float y2 = rois[n * 4 + 3];
    // FPN level routing: k = floor(4 + log2(sqrt(area)/224)), clip [2,5], -2
    float area = (y2 - y1) * (x2 - x1);
    float k = floorf(4.0f + log2f(sqrtf(area) / 224.0f));
    k = fminf(fmaxf(k, 2.0f), 5.0f);
    int lvl = (int)k - 2;                  // 0..3
    float scale = ldexpf(0.25f, -lvl);     // 0.25 / 2^lvl
    float x1s = x1 * scale;
    float y1s = y1 * scale;
    float rw = fmaxf(x2 * scale - x1s, 1.0f);
    float rh = fmaxf(y2 * scale - y1s, 1.0f);
    RoiMeta m;
    m.x1 = x1s;
    m.y1 = y1s;
    m.sx = rw / (float)(ROI_OUT * ROI_SR);
    m.sy = rh / (float)(ROI_OUT * ROI_SR);
    m.level = lvl;
    m.b = n / NROI_PER_B;
    m.pad0 = 0; m.pad1 = 0;
    meta[n] = m;
}

__global__ __launch_bounds__(256) void roi_align_kernel(
    const float* __restrict__ f0, const float* __restrict__ f1,
    const float* __restrict__ f2, const float* __restrict__ f3,
    const RoiMeta* __restrict__ meta, float* __restrict__ out, int total) {
    int idx = blockIdx.x * 256 + threadIdx.x;
    if (idx >= total) return;
    int pw = idx % ROI_OUT;
    int ph = (idx / ROI_OUT) % ROI_OUT;
    int c  = (idx / (ROI_OUT * ROI_OUT)) & (NCH - 1);
    int n  = idx / (ROI_OUT * ROI_OUT * NCH);

    RoiMeta m = meta[n];
    const float* f; int H, W;
    switch (m.level) {
        case 0:  f = f0; H = 200; W = 200; break;
        case 1:  f = f1; H = 100; W = 100; break;
        case 2:  f = f2; H = 50;  W = 50;  break;
        default: f = f3; H = 25;  W = 25;  break;
    }
    const float* fc = f + (size_t)(m.b * NCH + c) * H * W;

    float acc = 0.0f;
#pragma unroll
    for (int iy = 0; iy < ROI_SR; ++iy) {
        float y = m.y1 + ((float)(ph * ROI_SR + iy) + 0.5f) * m.sy;
        if (y < -1.0f || y > (float)H) continue;
        float yc = fminf(fmaxf(y, 0.0f), (float)(H - 1));
        int y0 = (int)floorf(yc);
        int y1i = min(y0 + 1, H - 1);
        float ly = yc - (float)y0;
        float hy = 1.0f - ly;
        const float* r0 = fc + (size_t)y0 * W;
        const float* r1 = fc + (size_t)y1i * W;
#pragma unroll
        for (int ix = 0; ix < ROI_SR; ++ix) {
            float x = m.x1 + ((float)(pw * ROI_SR + ix) + 0.5f) * m.sx;
            if (x < -1.0f || x > (float)W) continue;
            float xc = fminf(fmaxf(x, 0.0f), (float)(W - 1));
            int x0 = (int)floorf(xc);
            int x1i = min(x0 + 1, W - 1);
            float lx = xc - (float)x0;
            float hx = 1.0f - lx;
            acc += hy * (hx * r0[x0] + lx * r0[x1i]) +
                   ly * (hx * r1[x0] + lx * r1[x1i]);
        }
    }
    out[idx] = acc * 0.25f;  // mean over SR*SR samples
}

extern "C" void kernel_launch(void* const* d_in, const int* in_sizes, int n_in,
                              void* d_out, int out_size, void* d_ws, size_t ws_size,
                              hipStream_t stream) {
    const float* f0 = (const float*)d_in[0];
    const float* f1 = (const float*)d_in[1];
    const float* f2 = (const float*)d_in[2];
    const float* f3 = (const float*)d_in[3];
    const float* rois = (const float*)d_in[4];
    float* out = (float*)d_out;

    const int n_rois = 1024;            // B=2 * N=512
    RoiMeta* meta = (RoiMeta*)d_ws;     // 1024 * 32 B = 32 KB

    prep_rois_kernel<<<(n_rois + 255) / 256, 256, 0, stream>>>(rois, meta, n_rois);

    const int total = n_rois * NCH * ROI_OUT * ROI_OUT;  // 12,845,056
    roi_align_kernel<<<(total + 255) / 256, 256, 0, stream>>>(
        f0, f1, f2, f3, meta, out, total);
}

// Round 4
// 103.245 us; speedup vs baseline: 1.7285x; 1.7285x over previous
//
#include <hip/hip_runtime.h>

#define OUTS 7
#define SR 2
#define GRIDW 14   // OUTS*SR
#define NS 196     // 14*14 sample points per roi
#define NCH 256
#define NROI 1024
#define NBIN 49

// ---------------- NHWC fast path ----------------

// NHWC layout in workspace (floats):
//   lvl0 @ 0         : [2][200*200][256]
//   lvl1 @ 20480000  : [2][100*100][256]
//   lvl2 @ 25600000  : [2][ 50* 50][256]
//   lvl3 @ 26880000  : [2][ 25* 25][256]
#define WS_FLOATS 27200000

__global__ __launch_bounds__(256) void nchw_to_nhwc(const float* __restrict__ in,
                                                    float* __restrict__ out, int P) {
    __shared__ float tile[64][65];
    int p0 = blockIdx.x * 64;
    int c0 = blockIdx.y * 64;
    int b  = blockIdx.z;
    int tx = threadIdx.x;   // 0..63
    int ty = threadIdx.y;   // 0..3
    const float* inb = in + (size_t)b * NCH * P;
    float* outb = out + (size_t)b * P * NCH;
#pragma unroll
    for (int i = 0; i < 16; ++i) {
        int cl = ty * 16 + i;
        int p = p0 + tx;
        if (p < P) tile[cl][tx] = inb[(size_t)(c0 + cl) * P + p];
    }
    __syncthreads();
#pragma unroll
    for (int i = 0; i < 16; ++i) {
        int pl = ty * 16 + i;
        int p = p0 + pl;
        if (p < P) outb[(size_t)p * NCH + c0 + tx] = tile[tx][pl];
    }
}

__global__ __launch_bounds__(256) void roi_gather_nhwc(const float* __restrict__ nhwc,
                                                       const float* __restrict__ rois,
                                                       float* __restrict__ out) {
    __shared__ int   s_off[4][NS];
    __shared__ float s_w[4][NS];
    __shared__ float lds_out[NCH * NBIN];   // 50176 B

    int n = blockIdx.x;
    int tid = threadIdx.x;
    int b = n >> 9;   // n / 512

    // roi params (uniform across block; each thread recomputes)
    float x1 = rois[n * 4 + 0];
    float y1 = rois[n * 4 + 1];
    float x2 = rois[n * 4 + 2];
    float y2 = rois[n * 4 + 3];
    float area = (y2 - y1) * (x2 - x1);
    float kf = floorf(4.0f + log2f(sqrtf(area) / 224.0f));
    kf = fminf(fmaxf(kf, 2.0f), 5.0f);
    int lvl = (int)kf - 2;
    float scale = ldexpf(0.25f, -lvl);
    int H, W; size_t base;
    switch (lvl) {
        case 0:  H = 200; W = 200; base = 0;        break;
        case 1:  H = 100; W = 100; base = 20480000; break;
        case 2:  H = 50;  W = 50;  base = 25600000; break;
        default: H = 25;  W = 25;  base = 26880000; break;
    }
    float x1s = x1 * scale, y1s = y1 * scale;
    float rw = fmaxf(x2 * scale - x1s, 1.0f);
    float rh = fmaxf(y2 * scale - y1s, 1.0f);
    float sx = rw * (1.0f / GRIDW);
    float sy = rh * (1.0f / GRIDW);

    if (tid < NS) {
        int gy = tid / GRIDW, gx = tid % GRIDW;
        float y = y1s + ((float)gy + 0.5f) * sy;
        float x = x1s + ((float)gx + 0.5f) * sx;
        bool valid = (y >= -1.0f) && (y <= (float)H) && (x >= -1.0f) && (x <= (float)W);
        float yc = fminf(fmaxf(y, 0.0f), (float)(H - 1));
        float xc = fminf(fmaxf(x, 0.0f), (float)(W - 1));
        int y0 = (int)floorf(yc), x0 = (int)floorf(xc);
        int y1i = min(y0 + 1, H - 1), x1i = min(x0 + 1, W - 1);
        float ly = yc - (float)y0, lx = xc - (float)x0;
        float hy = 1.0f - ly, hx = 1.0f - lx;
        float vm = valid ? 1.0f : 0.0f;
        s_off[0][tid] = (y0 * W + x0) * NCH;
        s_off[1][tid] = (y0 * W + x1i) * NCH;
        s_off[2][tid] = (y1i * W + x0) * NCH;
        s_off[3][tid] = (y1i * W + x1i) * NCH;
        s_w[0][tid] = hy * hx * vm;
        s_w[1][tid] = hy * lx * vm;
        s_w[2][tid] = ly * hx * vm;
        s_w[3][tid] = ly * lx * vm;
    }
    __syncthreads();

    // lane = channel-quad: lane*4 .. lane*4+3 (64 lanes x float4 = all 256 ch).
    // Wave w owns bins {w, w+4, ...}: every (channel, bin) covered exactly once.
    int lane = tid & 63;
    int wave = tid >> 6;
    int c0 = lane * 4;
    const float* fc = nhwc + base + (size_t)b * (size_t)H * W * NCH + c0;

    for (int bin = wave; bin < NBIN; bin += 4) {
        int ph = bin / OUTS, pw = bin % OUTS;
        float4 acc = make_float4(0.f, 0.f, 0.f, 0.f);
#pragma unroll
        for (int iy = 0; iy < SR; ++iy) {
#pragma unroll
            for (int ix = 0; ix < SR; ++ix) {
                int s = (ph * SR + iy) * GRIDW + (pw * SR + ix);
#pragma unroll
                for (int t = 0; t < 4; ++t) {
                    float w = s_w[t][s];
                    float4 v = *(const float4*)(fc + s_off[t][s]);
                    acc.x += w * v.x;
                    acc.y += w * v.y;
                    acc.z += w * v.z;
                    acc.w += w * v.w;
                }
            }
        }
        lds_out[(c0 + 0) * NBIN + bin] = acc.x * 0.25f;
        lds_out[(c0 + 1) * NBIN + bin] = acc.y * 0.25f;
        lds_out[(c0 + 2) * NBIN + bin] = acc.z * 0.25f;
        lds_out[(c0 + 3) * NBIN + bin] = acc.w * 0.25f;
    }
    __syncthreads();

    const float4* lo = (const float4*)lds_out;
    float4* og = (float4*)(out + (size_t)n * (NCH * NBIN));
    for (int i = tid; i < (NCH * NBIN) / 4; i += 256) {
        og[i] = lo[i];
    }
}

// ---------------- fallback path (round-1, known-correct) ----------------

struct RoiMeta {
    float x1, y1, sx, sy;
    int level, b, pad0, pad1;
};

__global__ void prep_rois_kernel(const float* __restrict__ rois,
                                 RoiMeta* __restrict__ meta, int total) {
    int n = blockIdx.x * blockDim.x + threadIdx.x;
    if (n >= total) return;
    float x1 = rois[n * 4 + 0];
    float y1 = rois[n * 4 + 1];
    float x2 = rois[n * 4 + 2];
    float y2 = rois[n * 4 + 3];
    float area = (y2 - y1) * (x2 - x1);
    float k = floorf(4.0f + log2f(sqrtf(area) / 224.0f));
    k = fminf(fmaxf(k, 2.0f), 5.0f);
    int lvl = (int)k - 2;
    float scale = ldexpf(0.25f, -lvl);
    float x1s = x1 * scale;
    float y1s = y1 * scale;
    float rw = fmaxf(x2 * scale - x1s, 1.0f);
    float rh = fmaxf(y2 * scale - y1s, 1.0f);
    RoiMeta m;
    m.x1 = x1s; m.y1 = y1s;
    m.sx = rw / (float)(OUTS * SR);
    m.sy = rh / (float)(OUTS * SR);
    m.level = lvl;
    m.b = n / 512;
    m.pad0 = 0; m.pad1 = 0;
    meta[n] = m;
}

__global__ __launch_bounds__(256) void roi_align_kernel(
    const float* __restrict__ f0, const float* __restrict__ f1,
    const float* __restrict__ f2, const float* __restrict__ f3,
    const RoiMeta* __restrict__ meta, float* __restrict__ out, int total) {
    int idx = blockIdx.x * 256 + threadIdx.x;
    if (idx >= total) return;
    int pw = idx % OUTS;
    int ph = (idx / OUTS) % OUTS;
    int c  = (idx / (OUTS * OUTS)) & (NCH - 1);
    int n  = idx / (OUTS * OUTS * NCH);

    RoiMeta m = meta[n];
    const float* f; int H, W;
    switch (m.level) {
        case 0:  f = f0; H = 200; W = 200; break;
        case 1:  f = f1; H = 100; W = 100; break;
        case 2:  f = f2; H = 50;  W = 50;  break;
        default: f = f3; H = 25;  W = 25;  break;
    }
    const float* fc = f + (size_t)(m.b * NCH + c) * H * W;

    float acc = 0.0f;
#pragma unroll
    for (int iy = 0; iy < SR; ++iy) {
        float y = m.y1 + ((float)(ph * SR + iy) + 0.5f) * m.sy;
        if (y < -1.0f || y > (float)H) continue;
        float yc = fminf(fmaxf(y, 0.0f), (float)(H - 1));
        int y0 = (int)floorf(yc);
        int y1i = min(y0 + 1, H - 1);
        float ly = yc - (float)y0;
        float hy = 1.0f - ly;
        const float* r0 = fc + (size_t)y0 * W;
        const float* r1 = fc + (size_t)y1i * W;
#pragma unroll
        for (int ix = 0; ix < SR; ++ix) {
            float x = m.x1 + ((float)(pw * SR + ix) + 0.5f) * m.sx;
            if (x < -1.0f || x > (float)W) continue;
            float xc = fminf(fmaxf(x, 0.0f), (float)(W - 1));
            int x0 = (int)floorf(xc);
            int x1i = min(x0 + 1, W - 1);
            float lx = xc - (float)x0;
            float hx = 1.0f - lx;
            acc += hy * (hx * r0[x0] + lx * r0[x1i]) +
                   ly * (hx * r1[x0] + lx * r1[x1i]);
        }
    }
    out[idx] = acc * 0.25f;
}

// ---------------- launch ----------------

extern "C" void kernel_launch(void* const* d_in, const int* in_sizes, int n_in,
                              void* d_out, int out_size, void* d_ws, size_t ws_size,
                              hipStream_t stream) {
    const float* f0 = (const float*)d_in[0];
    const float* f1 = (const float*)d_in[1];
    const float* f2 = (const float*)d_in[2];
    const float* f3 = (const float*)d_in[3];
    const float* rois = (const float*)d_in[4];
    float* out = (float*)d_out;

    if (ws_size >= (size_t)WS_FLOATS * sizeof(float)) {
        float* nhwc = (float*)d_ws;
        dim3 blk(64, 4, 1);
        nchw_to_nhwc<<<dim3((40000 + 63) / 64, 4, 2), blk, 0, stream>>>(f0, nhwc + 0,        40000);
        nchw_to_nhwc<<<dim3((10000 + 63) / 64, 4, 2), blk, 0, stream>>>(f1, nhwc + 20480000, 10000);
        nchw_to_nhwc<<<dim3(( 2500 + 63) / 64, 4, 2), blk, 0, stream>>>(f2, nhwc + 25600000,  2500);
        nchw_to_nhwc<<<dim3((  625 + 63) / 64, 4, 2), blk, 0, stream>>>(f3, nhwc + 26880000,   625);
        roi_gather_nhwc<<<NROI, 256, 0, stream>>>(nhwc, rois, out);
    } else {
        RoiMeta* meta = (RoiMeta*)d_ws;
        prep_rois_kernel<<<(NROI + 255) / 256, 256, 0, stream>>>(rois, meta, NROI);
        const int total = NROI * NCH * OUTS * OUTS;
        roi_align_kernel<<<(total + 255) / 256, 256, 0, stream>>>(
            f0, f1, f2, f3, meta, out, total);
    }
}

// Round 5
// 72.592 us; speedup vs baseline: 2.4584x; 1.4223x over previous
//
#include <hip/hip_runtime.h>

#define OUTS 7
#define SR 2
#define GRIDW 14   // OUTS*SR
#define NS 196     // 14*14 sample points per roi
#define NCH 256
#define NROI 1024
#define NBIN 49

// bf16 NHWC workspace layout (ushort elements):
//   lvl0 @ 0         : [2][200*200][256]
//   lvl1 @ 20480000  : [2][100*100][256]
//   lvl2 @ 25600000  : [2][ 50* 50][256]
//   lvl3 @ 26880000  : [2][ 25* 25][256]
#define L0_OFF 0
#define L1_OFF 20480000
#define L2_OFF 25600000
#define L3_OFF 26880000
#define WS_ELEMS 27200000          // ushort elements (54.4 MB)

// pixel-tile counts per level (ceil(P/64)) and cumulative block ranges (x4 ctiles x2 batch)
// L0: 625 -> 5000 blocks, L1: 157 -> 1256, L2: 40 -> 320, L3: 10 -> 80; total 6656

static __device__ __forceinline__ unsigned short f2bf(float f) {
    unsigned u = __builtin_bit_cast(unsigned, f);
    u += 0x7fffu + ((u >> 16) & 1u);   // round-to-nearest-even
    return (unsigned short)(u >> 16);
}

__global__ __launch_bounds__(256) void nchw_to_nhwc_bf16(
    const float* __restrict__ f0, const float* __restrict__ f1,
    const float* __restrict__ f2, const float* __restrict__ f3,
    unsigned short* __restrict__ ws) {
    __shared__ float tile[64][65];
    int bid = blockIdx.x;
    const float* in; unsigned short* outp; int P, ptiles, local;
    if (bid < 5000)      { in = f0; outp = ws + L0_OFF; P = 40000; ptiles = 625; local = bid; }
    else if (bid < 6256) { in = f1; outp = ws + L1_OFF; P = 10000; ptiles = 157; local = bid - 5000; }
    else if (bid < 6576) { in = f2; outp = ws + L2_OFF; P = 2500;  ptiles = 40;  local = bid - 6256; }
    else                 { in = f3; outp = ws + L3_OFF; P = 625;   ptiles = 10;  local = bid - 6576; }
    int pt = local % ptiles;
    int rest = local / ptiles;
    int c0 = (rest & 3) * 64;
    int b  = rest >> 2;
    int p0 = pt * 64;
    int tx = threadIdx.x;   // 0..63
    int ty = threadIdx.y;   // 0..3
    const float* inb = in + (size_t)b * NCH * P;
    unsigned short* outb = outp + (size_t)b * P * NCH;

    int p = p0 + tx;
    if (p < P) {
#pragma unroll
        for (int i = 0; i < 16; ++i) {
            int cl = ty * 16 + i;
            tile[cl][tx] = inb[(size_t)(c0 + cl) * P + p];
        }
    }
    __syncthreads();
    // packed bf16 stores: each thread writes 2 consecutive channels as one uint
#pragma unroll
    for (int i = 0; i < 8; ++i) {
        int pl = ty * 16 + i * 2 + (tx >> 5);
        int cl = (tx & 31) * 2;
        int pp = p0 + pl;
        if (pp < P) {
            unsigned lo = f2bf(tile[cl][pl]);
            unsigned hi = f2bf(tile[cl + 1][pl]);
            *(unsigned*)(outb + (size_t)pp * NCH + c0 + cl) = lo | (hi << 16);
        }
    }
}

__global__ __launch_bounds__(256) void roi_gather_nhwc(
    const unsigned short* __restrict__ nhwc,
    const float* __restrict__ rois,
    float* __restrict__ out) {
    __shared__ int   s_off[4][NS];
    __shared__ float s_w[4][NS];
    __shared__ float lds_out[25 * 260];   // [col<=25][256 ch + pad4], 26000 B

    int n = blockIdx.x;
    int tid = threadIdx.x;
    int b = n >> 9;

    // roi params (uniform across block)
    float x1 = rois[n * 4 + 0];
    float y1 = rois[n * 4 + 1];
    float x2 = rois[n * 4 + 2];
    float y2 = rois[n * 4 + 3];
    float area = (y2 - y1) * (x2 - x1);
    float kf = floorf(4.0f + log2f(sqrtf(area) / 224.0f));
    kf = fminf(fmaxf(kf, 2.0f), 5.0f);
    int lvl = (int)kf - 2;
    float scale = ldexpf(0.25f, -lvl);
    int H, W; size_t base;
    switch (lvl) {
        case 0:  H = 200; W = 200; base = L0_OFF; break;
        case 1:  H = 100; W = 100; base = L1_OFF; break;
        case 2:  H = 50;  W = 50;  base = L2_OFF; break;
        default: H = 25;  W = 25;  base = L3_OFF; break;
    }
    float x1s = x1 * scale, y1s = y1 * scale;
    float rw = fmaxf(x2 * scale - x1s, 1.0f);
    float rh = fmaxf(y2 * scale - y1s, 1.0f);
    float sx = rw * (1.0f / GRIDW);
    float sy = rh * (1.0f / GRIDW);

    if (tid < NS) {
        int gy = tid / GRIDW, gx = tid % GRIDW;
        float y = y1s + ((float)gy + 0.5f) * sy;
        float x = x1s + ((float)gx + 0.5f) * sx;
        bool valid = (y >= -1.0f) && (y <= (float)H) && (x >= -1.0f) && (x <= (float)W);
        float yc = fminf(fmaxf(y, 0.0f), (float)(H - 1));
        float xc = fminf(fmaxf(x, 0.0f), (float)(W - 1));
        int y0 = (int)floorf(yc), x0 = (int)floorf(xc);
        int y1i = min(y0 + 1, H - 1), x1i = min(x0 + 1, W - 1);
        float ly = yc - (float)y0, lx = xc - (float)x0;
        float hy = 1.0f - ly, hx = 1.0f - lx;
        float vm = valid ? 1.0f : 0.0f;
        s_off[0][tid] = (y0 * W + x0) * NCH;
        s_off[1][tid] = (y0 * W + x1i) * NCH;
        s_off[2][tid] = (y1i * W + x0) * NCH;
        s_off[3][tid] = (y1i * W + x1i) * NCH;
        s_w[0][tid] = hy * hx * vm;
        s_w[1][tid] = hy * lx * vm;
        s_w[2][tid] = ly * hx * vm;
        s_w[3][tid] = ly * lx * vm;
    }
    __syncthreads();

    // lane = channel-quad (lane*4 .. lane*4+3); wave w owns bins {w, w+4, ...}
    int lane = tid & 63;
    int wave = tid >> 6;
    const unsigned short* fc = nhwc + base + (size_t)b * (size_t)H * W * NCH + lane * 4;
    float* og = out + (size_t)n * (NCH * NBIN);

#pragma unroll 2
    for (int pass = 0; pass < 2; ++pass) {
        const int b0 = pass * 24;
        const int ncol = pass ? 25 : 24;
        for (int bin = b0 + wave; bin < b0 + ncol; bin += 4) {
            int ph = bin / OUTS, pw = bin % OUTS;
            float4 acc = make_float4(0.f, 0.f, 0.f, 0.f);
#pragma unroll
            for (int iy = 0; iy < SR; ++iy) {
#pragma unroll
                for (int ix = 0; ix < SR; ++ix) {
                    int s = (ph * SR + iy) * GRIDW + (pw * SR + ix);
#pragma unroll
                    for (int t = 0; t < 4; ++t) {
                        float w = s_w[t][s];
                        uint2 v = *(const uint2*)(fc + s_off[t][s]);
                        float a0 = __builtin_bit_cast(float, v.x << 16);
                        float a1 = __builtin_bit_cast(float, v.x & 0xffff0000u);
                        float a2 = __builtin_bit_cast(float, v.y << 16);
                        float a3 = __builtin_bit_cast(float, v.y & 0xffff0000u);
                        acc.x += w * a0;
                        acc.y += w * a1;
                        acc.z += w * a2;
                        acc.w += w * a3;
                    }
                }
            }
            acc.x *= 0.25f; acc.y *= 0.25f; acc.z *= 0.25f; acc.w *= 0.25f;
            // bank-uniform 16B write: byte addr = 1040*(bin-b0) + 16*lane (16B aligned)
            *(float4*)&lds_out[(bin - b0) * 260 + lane * 4] = acc;
        }
        __syncthreads();
        // coalesced global write of this pass's columns
        for (int i = tid; i < NCH * ncol; i += 256) {
            int c = i / ncol, col = i - c * ncol;
            og[c * NBIN + b0 + col] = lds_out[col * 260 + c];
        }
        __syncthreads();
    }
}

// ---------------- fallback path (round-1, known-correct) ----------------

struct RoiMeta {
    float x1, y1, sx, sy;
    int level, b, pad0, pad1;
};

__global__ void prep_rois_kernel(const float* __restrict__ rois,
                                 RoiMeta* __restrict__ meta, int total) {
    int n = blockIdx.x * blockDim.x + threadIdx.x;
    if (n >= total) return;
    float x1 = rois[n * 4 + 0];
    float y1 = rois[n * 4 + 1];
    float x2 = rois[n * 4 + 2];
    float y2 = rois[n * 4 + 3];
    float area = (y2 - y1) * (x2 - x1);
    float k = floorf(4.0f + log2f(sqrtf(area) / 224.0f));
    k = fminf(fmaxf(k, 2.0f), 5.0f);
    int lvl = (int)k - 2;
    float scale = ldexpf(0.25f, -lvl);
    float x1s = x1 * scale;
    float y1s = y1 * scale;
    float rw = fmaxf(x2 * scale - x1s, 1.0f);
    float rh = fmaxf(y2 * scale - y1s, 1.0f);
    RoiMeta m;
    m.x1 = x1s; m.y1 = y1s;
    m.sx = rw / (float)(OUTS * SR);
    m.sy = rh / (float)(OUTS * SR);
    m.level = lvl;
    m.b = n / 512;
    m.pad0 = 0; m.pad1 = 0;
    meta[n] = m;
}

__global__ __launch_bounds__(256) void roi_align_kernel(
    const float* __restrict__ f0, const float* __restrict__ f1,
    const float* __restrict__ f2, const float* __restrict__ f3,
    const RoiMeta* __restrict__ meta, float* __restrict__ out, int total) {
    int idx = blockIdx.x * 256 + threadIdx.x;
    if (idx >= total) return;
    int pw = idx % OUTS;
    int ph = (idx / OUTS) % OUTS;
    int c  = (idx / (OUTS * OUTS)) & (NCH - 1);
    int n  = idx / (OUTS * OUTS * NCH);

    RoiMeta m = meta[n];
    const float* f; int H, W;
    switch (m.level) {
        case 0:  f = f0; H = 200; W = 200; break;
        case 1:  f = f1; H = 100; W = 100; break;
        case 2:  f = f2; H = 50;  W = 50;  break;
        default: f = f3; H = 25;  W = 25;  break;
    }
    const float* fc = f + (size_t)(m.b * NCH + c) * H * W;

    float acc = 0.0f;
#pragma unroll
    for (int iy = 0; iy < SR; ++iy) {
        float y = m.y1 + ((float)(ph * SR + iy) + 0.5f) * m.sy;
        if (y < -1.0f || y > (float)H) continue;
        float yc = fminf(fmaxf(y, 0.0f), (float)(H - 1));
        int y0 = (int)floorf(yc);
        int y1i = min(y0 + 1, H - 1);
        float ly = yc - (float)y0;
        float hy = 1.0f - ly;
        const float* r0 = fc + (size_t)y0 * W;
        const float* r1 = fc + (size_t)y1i * W;
#pragma unroll
        for (int ix = 0; ix < SR; ++ix) {
            float x = m.x1 + ((float)(pw * SR + ix) + 0.5f) * m.sx;
            if (x < -1.0f || x > (float)W) continue;
            float xc = fminf(fmaxf(x, 0.0f), (float)(W - 1));
            int x0 = (int)floorf(xc);
            int x1i = min(x0 + 1, W - 1);
            float lx = xc - (float)x0;
            float hx = 1.0f - lx;
            acc += hy * (hx * r0[x0] + lx * r0[x1i]) +
                   ly * (hx * r1[x0] + lx * r1[x1i]);
        }
    }
    out[idx] = acc * 0.25f;
}

// ---------------- launch ----------------

extern "C" void kernel_launch(void* const* d_in, const int* in_sizes, int n_in,
                              void* d_out, int out_size, void* d_ws, size_t ws_size,
                              hipStream_t stream) {
    const float* f0 = (const float*)d_in[0];
    const float* f1 = (const float*)d_in[1];
    const float* f2 = (const float*)d_in[2];
    const float* f3 = (const float*)d_in[3];
    const float* rois = (const float*)d_in[4];
    float* out = (float*)d_out;

    if (ws_size >= (size_t)WS_ELEMS * sizeof(unsigned short)) {
        unsigned short* nhwc = (unsigned short*)d_ws;
        nchw_to_nhwc_bf16<<<6656, dim3(64, 4, 1), 0, stream>>>(f0, f1, f2, f3, nhwc);
        roi_gather_nhwc<<<NROI, 256, 0, stream>>>(nhwc, rois, out);
    } else {
        RoiMeta* meta = (RoiMeta*)d_ws;
        prep_rois_kernel<<<(NROI + 255) / 256, 256, 0, stream>>>(rois, meta, NROI);
        const int total = NROI * NCH * OUTS * OUTS;
        roi_align_kernel<<<(total + 255) / 256, 256, 0, stream>>>(
            f0, f1, f2, f3, meta, out, total);
    }
}